// Round 18
// baseline (113.101 us; speedup 1.0000x reference)
//
#include <hip/hip_runtime.h>
#include <stdint.h>

// ColBERT MaxSim on MI355X (gfx950), round 24.
// scores[b,c] = sum_n max_s dot(qs[b,n,:], ps[c,s,:])
// qs: (64, 32, 128) f32, ps: (64, 1024, 128) f32, out: (64, 64) f32.
//
// R23 post-mortem: single-dispatch fused staging worked structurally (VGPR
// 120, no spill, FETCH = one f32 pass) but maxsim was 51 us, not 41: the
// staging added ~2000 cyc/iter of STALL (instruction cost is only ~250).
// Diagnosis: STAGE_LOAD's global loads have no consumer until STAGE_WRITE,
// so the scheduler SINKS them past the MFMA block to shorten F's live
// range -> zero overlap: compute(430) -> exposed L2 latency(~500) -> write
// -> barrier each iter = +13 us. Mirror image of the R3/R7 load-sink bug.
//
// R24 (one variable): bracket the compute with sched_barrier(0):
//   STAGE_LOAD; sched_barrier(0);   // loads can't sink below
//   compute (32 MFMA);
//   sched_barrier(0); STAGE_WRITE;  // F's waitcnt can't hoist into MFMAs
// Zero runtime instructions; T14 issue-early/write-late survives codegen.
// Everything else R23-verbatim (pins, layout, epilogue, grid 512).
// Predict: maxsim 51 -> 38-43, dur 111.3 -> 98-104 (session best), VGPR
// ~120, WRITE 16 B. Neutral (~50) or demotion (VGPR<96): revert R17 and
// declare the practical plateau (fill 43 + gaps + 38 structure ceiling).

typedef __bf16 bf16x8 __attribute__((ext_vector_type(8)));
typedef float floatx16 __attribute__((ext_vector_type(16)));

union FU { bf16x8 v; uint4 u; };

__device__ inline bf16x8 cvt8(const float4& a, const float4& b) {
  bf16x8 r;
  r[0] = (__bf16)a.x; r[1] = (__bf16)a.y; r[2] = (__bf16)a.z; r[3] = (__bf16)a.w;
  r[4] = (__bf16)b.x; r[5] = (__bf16)b.y; r[6] = (__bf16)b.z; r[7] = (__bf16)b.w;
  return r;
}

__device__ inline float rmax16(const floatx16& a) {
  // Nested fmaxf triples fuse to v_max3_f32.
  float m0 = fmaxf(fmaxf(a[0], a[1]), fmaxf(a[2], a[3]));
  float m1 = fmaxf(fmaxf(a[4], a[5]), fmaxf(a[6], a[7]));
  float m2 = fmaxf(fmaxf(a[8], a[9]), fmaxf(a[10], a[11]));
  float m3 = fmaxf(fmaxf(a[12], a[13]), fmaxf(a[14], a[15]));
  return fmaxf(fmaxf(m0, m1), fmaxf(m2, m3));
}

#define ZERO16 {0, 0, 0, 0, 0, 0, 0, 0, 0, 0, 0, 0, 0, 0, 0, 0}

__global__ __launch_bounds__(256) void maxsim_kernel(const float* __restrict__ qs,
                                                     const float* __restrict__ ps,
                                                     float* __restrict__ out) {
  const int lane = threadIdx.x & 63;
  const int wave = threadIdx.x >> 6;

  // XCD swizzle: the 8 blocks of doc c all land on XCD c>>3 -> P_c (512 KB
  // f32) L2-resident after the first reader (per-XCD set: 8 docs = 4 MB).
  const int xcd = blockIdx.x & 7;
  const int slot = blockIdx.x >> 3;   // 0..63
  const int c = xcd * 8 + (slot >> 3);
  const int bg = slot & 7;
  const int qb0 = bg * 8 + wave * 2;  // this wave's first query (of 2)

  const int row = lane & 31;          // A-frag: s-row; B-frag: query token n
  const int hi8 = (lane >> 5) * 8;    // K-half selector (elements)

  // Q B-frags f32 -> cvt -> reg in the PROLOGUE (R14-proven safe), then
  // PINNED per 32-bit component (R21-proven): remat impossible.
  // qf[bb][k] = Q[qb0+bb][n=row][k*16 + hi8 + 0..7] as bf16 (64 VGPRs).
  uint4 qf[2][8];
#pragma unroll
  for (int bb = 0; bb < 2; ++bb) {
    const float* q = qs + ((qb0 + bb) * 32 + row) * 128 + hi8;
#pragma unroll
    for (int k = 0; k < 8; ++k) {
      float4 a = *(const float4*)(q + k * 16);
      float4 b = *(const float4*)(q + k * 16 + 4);
      FU f; f.v = cvt8(a, b);
      qf[bb][k] = f.u;
    }
  }
#pragma unroll
  for (int bb = 0; bb < 2; ++bb)
#pragma unroll
    for (int k = 0; k < 8; ++k)
      asm volatile("" : "+v"(qf[bb][k].x), "+v"(qf[bb][k].y),
                        "+v"(qf[bb][k].z), "+v"(qf[bb][k].w));

  // P tile double-buffer, bf16, 64 tokens/tile = 16 KiB each, A-frag order:
  // sub-tile u (32 rows) at u*8192 B, chunk j (=k) at j*1024 B, lane at 16 B.
  __shared__ __align__(16) ushort lds_p[2][8192];

  // Per-lane f32 global element offset (tile tt adds tt*64*128).
  const float* pg = ps + (c * 1024 + row) * 128 + hi8;

  // Wave w stages chunks m = 4w..4w+3 (u = m>>3, j = m&7): per chunk, 2
  // float4 loads; lane l covers row u*32+(l&31), dims j*16+(l>>5)*8+0..7.
  float4 F[8];

#define STAGE_LOAD(tt)                                                        \
  _Pragma("unroll") for (int jj = 0; jj < 4; ++jj) {                          \
    const int m = wave * 4 + jj;                                              \
    const int u = m >> 3, j = m & 7;                                          \
    const float* src = pg + (tt) * 8192 + u * 32 * 128 + j * 16;              \
    F[2 * jj] = *(const float4*)src;                                          \
    F[2 * jj + 1] = *(const float4*)(src + 4);                                \
  }

#define STAGE_WRITE(B)                                                        \
  _Pragma("unroll") for (int jj = 0; jj < 4; ++jj) {                          \
    const int m = wave * 4 + jj;                                              \
    const int u = m >> 3, j = m & 7;                                          \
    *(bf16x8*)(&(B)[u * 4096 + j * 512 + lane * 8]) =                         \
        cvt8(F[2 * jj], F[2 * jj + 1]);                                       \
  }

  // Prologue: stage tile 0.
  STAGE_LOAD(0)
  STAGE_WRITE(lds_p[0])
  __syncthreads();

  float vmax0 = -3.4e38f, vmax1 = -3.4e38f;
  int cb = 0;

#pragma unroll 1
  for (int t = 0; t < 16; ++t) {
    // T14: issue next tile's f32 loads NOW. The sched_barrier pins them
    // here -- the scheduler may NOT sink them past the MFMA block (that
    // sinking was R23's +13 us of exposed L2 latency).
    if (t < 15) {
      STAGE_LOAD(t + 1)
    }
    __builtin_amdgcn_sched_barrier(0);
    // Compute tile t (R13's best mapping: 2 subtiles x 2 queries, 2 chains).
    const ushort* lp = &lds_p[cb][0] + lane * 8;
#pragma unroll
    for (int u = 0; u < 2; ++u) {
      floatx16 acc0 = ZERO16, acc1 = ZERO16;
#pragma unroll
      for (int k = 0; k < 8; ++k) {
        bf16x8 af = *(const bf16x8*)(lp + u * 4096 + k * 512);
        FU f0; f0.u = qf[0][k];
        FU f1; f1.u = qf[1][k];
        acc0 = __builtin_amdgcn_mfma_f32_32x32x16_bf16(af, f0.v, acc0, 0, 0, 0);
        acc1 = __builtin_amdgcn_mfma_f32_32x32x16_bf16(af, f1.v, acc1, 0, 0, 0);
      }
      vmax0 = fmaxf(vmax0, rmax16(acc0));
      vmax1 = fmaxf(vmax1, rmax16(acc1));
    }
    __builtin_amdgcn_sched_barrier(0);
    // Write staged tile t+1 (vmcnt wait lands HERE, after the compute that
    // covered the latency), then barrier.
    if (t < 15) {
      STAGE_WRITE(lds_p[cb ^ 1])
    }
    __syncthreads();
    cb ^= 1;
  }

  // acc D-layout: col = lane&31 = token n; lanes l, l^32 hold complementary
  // row-halves -> max-merge, then butterfly-sum the 32 tokens.
  vmax0 = fmaxf(vmax0, __shfl_xor(vmax0, 32, 64));
  vmax1 = fmaxf(vmax1, __shfl_xor(vmax1, 32, 64));
#pragma unroll
  for (int o = 16; o > 0; o >>= 1) {
    vmax0 += __shfl_xor(vmax0, o, 64);
    vmax1 += __shfl_xor(vmax1, o, 64);
  }
  if (lane == 0) {
    out[(qb0 + 0) * 64 + c] = vmax0;
    out[(qb0 + 1) * 64 + c] = vmax1;
  }
}

extern "C" void kernel_launch(void* const* d_in, const int* in_sizes, int n_in,
                              void* d_out, int out_size, void* d_ws, size_t ws_size,
                              hipStream_t stream) {
  const float* qs = (const float*)d_in[0];
  const float* ps = (const float*)d_in[1];
  float* out = (float*)d_out;
  (void)d_ws; (void)ws_size;  // ws poison fill is unconditional; ws gives us nothing

  maxsim_kernel<<<dim3(512), dim3(256), 0, stream>>>(qs, ps, out);
}